// Round 1
// baseline (721.092 us; speedup 1.0000x reference)
//
#include <hip/hip_runtime.h>

#define T_N 256
#define U_N 512
#define H_N 64
#define P_N 1024

typedef __attribute__((ext_vector_type(8))) short short8;
typedef __attribute__((ext_vector_type(4))) float f32x4;

__device__ __forceinline__ short f2bf(float f) {
  union { float f; unsigned u; } v; v.f = f;
  unsigned r = v.u + 0x7FFFu + ((v.u >> 16) & 1u);
  return (short)(r >> 16);
}

// ---------------- GRU: one block per user, 192 threads (one per gate col) ----
__global__ __launch_bounds__(192) void k_gru(
    const int* __restrict__ x, const float* __restrict__ poi_emb,
    const float* __restrict__ h0, const float* __restrict__ Wx,
    const float* __restrict__ Wh, const float* __restrict__ b,
    float* __restrict__ out, float* __restrict__ hT) {
  int u = blockIdx.x;
  int j = threadIdx.x;  // 0..191
  __shared__ __align__(16) float xt_lds[H_N];
  __shared__ __align__(16) float h_lds[H_N];
  __shared__ float gs[128];
  __shared__ float gnx[H_N], gnh[H_N];
  __shared__ int xi[T_N];
  float wxr[H_N], whr[H_N];
#pragma unroll
  for (int k = 0; k < H_N; ++k) {
    wxr[k] = Wx[k * 192 + j];
    whr[k] = Wh[k * 192 + j];
  }
  float bj = b[j];
  for (int tt = j; tt < T_N; tt += 192) xi[tt] = x[tt * U_N + u];
  if (j < H_N) h_lds[j] = h0[u * H_N + j];
  __syncthreads();
  float xcur = 0.f;
  if (j < H_N) xcur = poi_emb[xi[0] * H_N + j];
  for (int t = 0; t < T_N; ++t) {
    if (j < H_N) xt_lds[j] = xcur;
    __syncthreads();
    if (j < H_N && t + 1 < T_N) xcur = poi_emb[xi[t + 1] * H_N + j];  // prefetch
    float gx0 = 0.f, gx1 = 0.f, gh0 = 0.f, gh1 = 0.f;
#pragma unroll
    for (int k4 = 0; k4 < 16; ++k4) {
      float4 xv = *(const float4*)&xt_lds[k4 * 4];
      float4 hv = *(const float4*)&h_lds[k4 * 4];
      float px = xv.x * wxr[k4 * 4] + xv.y * wxr[k4 * 4 + 1] +
                 xv.z * wxr[k4 * 4 + 2] + xv.w * wxr[k4 * 4 + 3];
      float ph = hv.x * whr[k4 * 4] + hv.y * whr[k4 * 4 + 1] +
                 hv.z * whr[k4 * 4 + 2] + hv.w * whr[k4 * 4 + 3];
      if (k4 & 1) { gx1 += px; gh1 += ph; } else { gx0 += px; gh0 += ph; }
    }
    float gx = gx0 + gx1 + bj;
    float gh = gh0 + gh1;
    if (j < 128) gs[j] = gx + gh;
    else { gnx[j - 128] = gx; gnh[j - 128] = gh; }
    __syncthreads();
    if (j < H_N) {
      float r = 1.f / (1.f + __expf(-gs[j]));
      float z = 1.f / (1.f + __expf(-gs[64 + j]));
      float nx = gnx[j] + r * gnh[j];
      float e2 = __expf(2.f * nx);
      float n = 1.f - 2.f / (e2 + 1.f);  // tanh, overflow-safe
      float hp = h_lds[j];
      float hn = (1.f - z) * hp + z * n;
      out[((size_t)t * U_N + u) * H_N + j] = hn;
      h_lds[j] = hn;
    }
  }
  __syncthreads();
  if (j < H_N) hT[u * H_N + j] = h_lds[j];
}

// ---------------- per-user bias: ub[u,p] = fc_b[p] + p_u . fc_W[64:128] -----
__global__ __launch_bounds__(256) void k_ub(
    const int* __restrict__ active_user, const float* __restrict__ user_emb,
    const float* __restrict__ fcW, const float* __restrict__ fcb,
    float* __restrict__ ub) {
  int u = blockIdx.x;
  int tid = threadIdx.x;
  __shared__ float pu[H_N];
  if (tid < H_N) pu[tid] = user_emb[active_user[u] * H_N + tid];
  __syncthreads();
  for (int p = tid; p < P_N; p += 256) {
    float acc = fcb[p];
#pragma unroll
    for (int k = 0; k < H_N; ++k) acc += pu[k] * fcW[(H_N + k) * P_N + p];
    ub[u * P_N + p] = acc;
  }
}

// ---------------- pack fc_W[0:64] into MFMA-fragment-order bf16 -------------
// Bp[((ks*4+kg)*1024 + col)*8 + e] = B[ks*32 + kg*8 + e][col]
__global__ __launch_bounds__(256) void k_bpack(const float* __restrict__ fcW,
                                               short* __restrict__ bp) {
  int idx = blockIdx.x * 256 + threadIdx.x;  // 8192 = 2*4*1024
  int col = idx & 1023;
  int kg = (idx >> 10) & 3;
  int ks = idx >> 12;
#pragma unroll
  for (int e = 0; e < 8; ++e) {
    int k = ks * 32 + kg * 8 + e;
    bp[((size_t)((ks * 4 + kg) * P_N + col)) * 8 + e] = f2bf(fcW[k * P_N + col]);
  }
}

// ---------------- decay-weighted sum: block per (user, 64-row i-tile) -------
__global__ __launch_bounds__(256) void k_stage2(
    const float* __restrict__ t, const float* __restrict__ s,
    const float* __restrict__ out, float* __restrict__ out_w) {
  int u = blockIdx.x >> 2;
  int tile = blockIdx.x & 3;
  int i0 = tile * 64;
  int tid = threadIdx.x;
  __shared__ __align__(16) float outU[T_N][H_N];   // 64 KB
  __shared__ float tU[T_N];
  __shared__ float sU[T_N][2];
  __shared__ __align__(16) float wq[T_N][4];       // 4 KB
  __shared__ float pacc[4][4][H_N];                // 4 KB
  __shared__ __align__(16) float sums[4][4];
  int jmax = i0 + 64;  // rows j < jmax are ever needed
  for (int idx = tid; idx < jmax * 16; idx += 256) {
    int jr = idx >> 4, q = idx & 15;
    *(float4*)&outU[jr][q * 4] =
        *(const float4*)&out[((size_t)jr * U_N + u) * H_N + q * 4];
  }
  for (int jr = tid; jr < jmax; jr += 256) {
    tU[jr] = t[jr * U_N + u];
    sU[jr][0] = s[((size_t)jr * U_N + u) * 2];
    sU[jr][1] = s[((size_t)jr * U_N + u) * 2 + 1];
  }
  __syncthreads();
  int h = tid & 63, jg = tid >> 6;
  for (int q = 0; q < 16; ++q) {
    int ibase = i0 + q * 4;
    // 1. compute w for 4 rows (i = ibase..ibase+3), this thread's j = tid
    int j = tid;
    float4 wv = {0.f, 0.f, 0.f, 0.f};
    if (j < jmax) {
      float tj = tU[j], sx = sU[j][0], sy = sU[j][1];
#pragma unroll
      for (int e = 0; e < 4; ++e) {
        int i = ibase + e;
        if (j <= i) {
          float dt = tU[i] - tj;
          float dx = sU[i][0] - sx, dy = sU[i][1] - sy;
          float dsn = sqrtf(dx * dx + dy * dy);
          float ft = 0.5f * (__cosf(dt * 7.2722052166430395e-05f) + 1.0f) *
                     __expf(dt * (-1.1574074074074074e-06f));
          float fs = __expf(-100.0f * dsn);
          (&wv.x)[e] = ft * fs + 1e-10f;
        }
      }
    }
    *(float4*)&wq[j][0] = wv;
    // wave-reduce partial sums of w (per i)
    float4 sv = wv;
#pragma unroll
    for (int off = 32; off; off >>= 1) {
      sv.x += __shfl_xor(sv.x, off);
      sv.y += __shfl_xor(sv.y, off);
      sv.z += __shfl_xor(sv.z, off);
      sv.w += __shfl_xor(sv.w, off);
    }
    if ((tid & 63) == 0) *(float4*)&sums[jg][0] = sv;
    __syncthreads();
    // 2. matvec: thread (h, jg) accumulates 4 i's over its j-range
    float4 acc = {0.f, 0.f, 0.f, 0.f};
    int je = ibase + 4 - jg * 64;
    if (je > 64) je = 64;
    for (int jj = 0; jj < je; ++jj) {
      int jr = jg * 64 + jj;
      float o = outU[jr][h];
      float4 w4 = *(const float4*)&wq[jr][0];
      acc.x += w4.x * o; acc.y += w4.y * o;
      acc.z += w4.z * o; acc.w += w4.w * o;
    }
    pacc[jg][0][h] = acc.x; pacc[jg][1][h] = acc.y;
    pacc[jg][2][h] = acc.z; pacc[jg][3][h] = acc.w;
    __syncthreads();
    {
      int e = jg;
      float v = pacc[0][e][h] + pacc[1][e][h] + pacc[2][e][h] + pacc[3][e][h];
      float sw = sums[0][e] + sums[1][e] + sums[2][e] + sums[3][e];
      int i = ibase + e;
      out_w[((size_t)i * U_N + u) * H_N + h] = v / sw;
    }
    __syncthreads();  // protect wq/pacc reuse
  }
}

// ---------------- FC: y = out_w @ fc_W[0:64] + ub  (bf16 MFMA) --------------
__global__ __launch_bounds__(256) void k_fc(
    const float* __restrict__ A, const short* __restrict__ Bp,
    const float* __restrict__ ub, float* __restrict__ C) {
  int bm = blockIdx.y, bn = blockIdx.x;
  int tid = threadIdx.x;
  int wave = tid >> 6, lane = tid & 63;
  int wm = wave >> 1, wn = wave & 1;
  int row0 = bm * 128 + wm * 64;
  int col0 = bn * 128 + wn * 64;
  int lr = lane & 15, lk = lane >> 4;
  f32x4 acc[4][4] = {};
#pragma unroll
  for (int ks = 0; ks < 2; ++ks) {
    short8 af[4];
#pragma unroll
    for (int m = 0; m < 4; ++m) {
      const float* ap = &A[((size_t)(row0 + m * 16 + lr)) * H_N + ks * 32 + lk * 8];
      float4 v0 = *(const float4*)ap;
      float4 v1 = *(const float4*)(ap + 4);
      short8 av;
      av[0] = f2bf(v0.x); av[1] = f2bf(v0.y); av[2] = f2bf(v0.z); av[3] = f2bf(v0.w);
      av[4] = f2bf(v1.x); av[5] = f2bf(v1.y); av[6] = f2bf(v1.z); av[7] = f2bf(v1.w);
      af[m] = av;
    }
#pragma unroll
    for (int n = 0; n < 4; ++n) {
      short8 bf = *(const short8*)&Bp[((size_t)((ks * 4 + lk) * P_N + col0 + n * 16 + lr)) * 8];
#pragma unroll
      for (int m = 0; m < 4; ++m)
        acc[m][n] = __builtin_amdgcn_mfma_f32_16x16x32_bf16(af[m], bf, acc[m][n], 0, 0, 0);
    }
  }
#pragma unroll
  for (int m = 0; m < 4; ++m) {
    int rbase = row0 + m * 16 + lk * 4;
#pragma unroll
    for (int n = 0; n < 4; ++n) {
      int c = col0 + n * 16 + lr;
#pragma unroll
      for (int r = 0; r < 4; ++r) {
        int row = rbase + r;
        int uu = row & (U_N - 1);
        C[(size_t)row * P_N + c] = acc[m][n][r] + ub[uu * P_N + c];
      }
    }
  }
}

extern "C" void kernel_launch(void* const* d_in, const int* in_sizes, int n_in,
                              void* d_out, int out_size, void* d_ws, size_t ws_size,
                              hipStream_t stream) {
  const int*   x           = (const int*)d_in[0];
  const float* t           = (const float*)d_in[1];
  // d_in[2] t_slot unused; d_in[4] y unused
  const float* s           = (const float*)d_in[3];
  const float* h0          = (const float*)d_in[5];
  const int*   active_user = (const int*)d_in[6];
  const float* poi_emb     = (const float*)d_in[7];
  const float* user_emb    = (const float*)d_in[8];
  const float* Wx          = (const float*)d_in[9];
  const float* Wh          = (const float*)d_in[10];
  const float* b           = (const float*)d_in[11];
  const float* fcW         = (const float*)d_in[12];
  const float* fcb         = (const float*)d_in[13];

  float* y_out = (float*)d_out;
  float* hT = y_out + (size_t)T_N * U_N * P_N;

  char* ws = (char*)d_ws;
  float* out_buf = (float*)ws;                          // 33,554,432 B
  float* outw    = (float*)(ws + 33554432);             // 33,554,432 B
  float* ub      = (float*)(ws + 67108864);             // 2,097,152 B
  short* bp      = (short*)(ws + 69206016);             // 131,072 B

  k_gru<<<U_N, 192, 0, stream>>>(x, poi_emb, h0, Wx, Wh, b, out_buf, hT);
  k_ub<<<U_N, 256, 0, stream>>>(active_user, user_emb, fcW, fcb, ub);
  k_bpack<<<32, 256, 0, stream>>>(fcW, bp);
  k_stage2<<<U_N * 4, 256, 0, stream>>>(t, s, out_buf, outw);
  k_fc<<<dim3(8, 1024), 256, 0, stream>>>(outw, bp, ub, y_out);
}

// Round 2
// 701.419 us; speedup vs baseline: 1.0280x; 1.0280x over previous
//
#include <hip/hip_runtime.h>

#define T_N 256
#define U_N 512
#define H_N 64
#define P_N 1024

typedef __attribute__((ext_vector_type(8))) short short8;
typedef __attribute__((ext_vector_type(4))) float f32x4;

#define MFMA __builtin_amdgcn_mfma_f32_16x16x32_bf16

__device__ __forceinline__ short f2bf(float f) {
  union { float f; unsigned u; } v; v.f = f;
  unsigned r = v.u + 0x7FFFu + ((v.u >> 16) & 1u);
  return (short)(r >> 16);
}

__device__ __forceinline__ short8 pack8(float4 a, float4 b) {
  short8 r;
  r[0] = f2bf(a.x); r[1] = f2bf(a.y); r[2] = f2bf(a.z); r[3] = f2bf(a.w);
  r[4] = f2bf(b.x); r[5] = f2bf(b.y); r[6] = f2bf(b.z); r[7] = f2bf(b.w);
  return r;
}

// ---- pack Wx/Wh (64x192) into bf16 B-fragments: wp[((ks*4+lk)*192+g)*8+e] ---
__global__ __launch_bounds__(256) void k_wpack(
    const float* __restrict__ Wx, const float* __restrict__ Wh,
    short* __restrict__ wxp, short* __restrict__ whp) {
  int idx = blockIdx.x * 256 + threadIdx.x;  // 3072 = 2*1536
  int m = idx / 1536;
  int r = idx % 1536;
  const float* W = m ? Wh : Wx;
  short* op = m ? whp : wxp;
  int ks = r / 768, lk = (r / 192) & 3, g = r % 192;
#pragma unroll
  for (int e = 0; e < 8; ++e)
    op[(size_t)r * 8 + e] = f2bf(W[(ks * 32 + lk * 8 + e) * 192 + g]);
}

// ---- fused GRU scan: 32 blocks x 16 users, MFMA gates -----------------------
__global__ __launch_bounds__(256) void k_scan(
    const int* __restrict__ x, const float* __restrict__ poi_emb,
    const float* __restrict__ h0, const short* __restrict__ wxp,
    const short* __restrict__ whp, const float* __restrict__ b,
    float* __restrict__ out, float* __restrict__ hT) {
  int u0 = blockIdx.x * 16;
  int tid = threadIdx.x;
  int w = tid >> 6, lane = tid & 63, lr = lane & 15, lk = lane >> 4;
  __shared__ __align__(16) float h_lds[2][16][68];
  int sgr = 16 * w, sgz = 64 + 16 * w, sgn = 128 + 16 * w;
  short8 fxr[2], fxz[2], fxn[2], fhr[2], fhz[2], fhn[2];
#pragma unroll
  for (int ks = 0; ks < 2; ++ks) {
    size_t base = (size_t)((ks * 4 + lk) * 192) * 8;
    fxr[ks] = *(const short8*)&wxp[base + (size_t)(sgr + lr) * 8];
    fxz[ks] = *(const short8*)&wxp[base + (size_t)(sgz + lr) * 8];
    fxn[ks] = *(const short8*)&wxp[base + (size_t)(sgn + lr) * 8];
    fhr[ks] = *(const short8*)&whp[base + (size_t)(sgr + lr) * 8];
    fhz[ks] = *(const short8*)&whp[base + (size_t)(sgz + lr) * 8];
    fhn[ks] = *(const short8*)&whp[base + (size_t)(sgn + lr) * 8];
  }
  float br = b[sgr + lr], bz = b[sgz + lr], bn = b[sgn + lr];
  for (int idx = tid; idx < 16 * 64; idx += 256)
    h_lds[0][idx >> 6][idx & 63] = h0[(size_t)(u0 + (idx >> 6)) * H_N + (idx & 63)];
  __syncthreads();
  float hp[4];
#pragma unroll
  for (int e = 0; e < 4; ++e) hp[e] = h_lds[0][4 * lk + e][16 * w + lr];
  short8 ah0, ah1;
  {
    float4 q0 = *(float4*)&h_lds[0][lr][8 * lk];
    float4 q1 = *(float4*)&h_lds[0][lr][8 * lk + 4];
    float4 q2 = *(float4*)&h_lds[0][lr][32 + 8 * lk];
    float4 q3 = *(float4*)&h_lds[0][lr][32 + 8 * lk + 4];
    ah0 = pack8(q0, q1); ah1 = pack8(q2, q3);
  }
  // prefetch x_emb pipeline
  int xic = x[u0 + lr];
  float4 p0, p1, p2, p3;
  {
    const float* pb = poi_emb + (size_t)xic * H_N + lk * 8;
    p0 = *(const float4*)pb; p1 = *(const float4*)(pb + 4);
    p2 = *(const float4*)(pb + 32); p3 = *(const float4*)(pb + 36);
  }
  int xin = x[U_N + u0 + lr];
  for (int t = 0; t < T_N; ++t) {
    short8 ax0 = pack8(p0, p1), ax1 = pack8(p2, p3);
    if (t + 1 < T_N) {
      const float* pb = poi_emb + (size_t)xin * H_N + lk * 8;
      p0 = *(const float4*)pb; p1 = *(const float4*)(pb + 4);
      p2 = *(const float4*)(pb + 32); p3 = *(const float4*)(pb + 36);
      int tn = (t + 2 < T_N) ? t + 2 : T_N - 1;
      xin = x[(size_t)tn * U_N + u0 + lr];
    }
    f32x4 accr = {br, br, br, br};
    f32x4 accz = {bz, bz, bz, bz};
    f32x4 accnx = {bn, bn, bn, bn};
    f32x4 accnh = {0.f, 0.f, 0.f, 0.f};
    accr = MFMA(ax0, fxr[0], accr, 0, 0, 0);
    accr = MFMA(ax1, fxr[1], accr, 0, 0, 0);
    accz = MFMA(ax0, fxz[0], accz, 0, 0, 0);
    accz = MFMA(ax1, fxz[1], accz, 0, 0, 0);
    accnx = MFMA(ax0, fxn[0], accnx, 0, 0, 0);
    accnx = MFMA(ax1, fxn[1], accnx, 0, 0, 0);
    accr = MFMA(ah0, fhr[0], accr, 0, 0, 0);
    accr = MFMA(ah1, fhr[1], accr, 0, 0, 0);
    accz = MFMA(ah0, fhz[0], accz, 0, 0, 0);
    accz = MFMA(ah1, fhz[1], accz, 0, 0, 0);
    accnh = MFMA(ah0, fhn[0], accnh, 0, 0, 0);
    accnh = MFMA(ah1, fhn[1], accnh, 0, 0, 0);
    int wbuf = (t & 1) ^ 1;
#pragma unroll
    for (int e = 0; e < 4; ++e) {
      float r = 1.f / (1.f + __expf(-accr[e]));
      float z = 1.f / (1.f + __expf(-accz[e]));
      float npre = accnx[e] + r * accnh[e];
      float e2 = __expf(2.f * npre);
      float n = 1.f - 2.f / (e2 + 1.f);
      float hn = hp[e] + z * (n - hp[e]);
      hp[e] = hn;
      h_lds[wbuf][4 * lk + e][16 * w + lr] = hn;
      out[((size_t)t * U_N + u0 + 4 * lk + e) * H_N + 16 * w + lr] = hn;
    }
    __syncthreads();
    {
      float4 q0 = *(float4*)&h_lds[wbuf][lr][8 * lk];
      float4 q1 = *(float4*)&h_lds[wbuf][lr][8 * lk + 4];
      float4 q2 = *(float4*)&h_lds[wbuf][lr][32 + 8 * lk];
      float4 q3 = *(float4*)&h_lds[wbuf][lr][32 + 8 * lk + 4];
      ah0 = pack8(q0, q1); ah1 = pack8(q2, q3);
    }
  }
  // final state is in buffer 0 (t=255 wrote wbuf=0); in-loop barrier covers it
  for (int idx = tid; idx < 16 * 64; idx += 256)
    hT[(size_t)(u0 + (idx >> 6)) * H_N + (idx & 63)] = h_lds[0][idx >> 6][idx & 63];
}

// ---- per-user bias: ub[u,p] = fc_b[p] + p_u . fc_W[64:128] ------------------
__global__ __launch_bounds__(256) void k_ub(
    const int* __restrict__ active_user, const float* __restrict__ user_emb,
    const float* __restrict__ fcW, const float* __restrict__ fcb,
    float* __restrict__ ub) {
  int u = blockIdx.x;
  int tid = threadIdx.x;
  __shared__ float pu[H_N];
  if (tid < H_N) pu[tid] = user_emb[active_user[u] * H_N + tid];
  __syncthreads();
  for (int p = tid; p < P_N; p += 256) {
    float acc = fcb[p];
#pragma unroll
    for (int k = 0; k < H_N; ++k) acc += pu[k] * fcW[(H_N + k) * P_N + p];
    ub[u * P_N + p] = acc;
  }
}

// ---- pack fc_W[0:64] into MFMA B-fragment order bf16 ------------------------
__global__ __launch_bounds__(256) void k_bpack(const float* __restrict__ fcW,
                                               short* __restrict__ bp) {
  int idx = blockIdx.x * 256 + threadIdx.x;  // 8192
  int col = idx & 1023;
  int kg = (idx >> 10) & 3;
  int ks = idx >> 12;
#pragma unroll
  for (int e = 0; e < 8; ++e) {
    int k = ks * 32 + kg * 8 + e;
    bp[((size_t)((ks * 4 + kg) * P_N + col)) * 8 + e] = f2bf(fcW[k * P_N + col]);
  }
}

// ---- decay-weighted sum: block per user, register-blocked 4i x 4h -----------
__global__ __launch_bounds__(256) void k_stage2(
    const float* __restrict__ t, const float* __restrict__ s,
    const float* __restrict__ out, float* __restrict__ out_w) {
  int u = blockIdx.x;
  int tid = threadIdx.x;
  __shared__ __align__(16) float outU[T_N][68];  // stride 68 -> uniform banks
  __shared__ __align__(16) float wl[T_N][20];
  __shared__ float tU[T_N];
  __shared__ float sUx[T_N], sUy[T_N];
  for (int idx = tid; idx < T_N * 16; idx += 256) {
    int jr = idx >> 4, q = idx & 15;
    *(float4*)&outU[jr][q * 4] =
        *(const float4*)&out[((size_t)jr * U_N + u) * H_N + q * 4];
  }
  {
    int jr = tid;
    tU[jr] = t[jr * U_N + u];
    sUx[jr] = s[((size_t)jr * U_N + u) * 2];
    sUy[jr] = s[((size_t)jr * U_N + u) * 2 + 1];
  }
  __syncthreads();
  int lane = tid & 63, wv = tid >> 6;
  int h4 = lane & 15, jsub = lane >> 4;
  int j = tid;
  float tj = tU[j], sx = sUx[j], sy = sUy[j];
  for (int c = 0; c < 16; ++c) {
    int jmaxc = c * 16 + 16;
    if (j < jmaxc) {
      float w16[16];
#pragma unroll
      for (int iq = 0; iq < 16; ++iq) {
        int i = c * 16 + iq;
        float wv_ = 0.f;
        if (j <= i) {
          float dt = tU[i] - tj;
          float dx = sUx[i] - sx, dy = sUy[i] - sy;
          float dsn = sqrtf(dx * dx + dy * dy);
          float ft = 0.5f * (__cosf(dt * 7.2722052166430395e-05f) + 1.0f) *
                     __expf(dt * (-1.1574074074074074e-06f));
          wv_ = ft * __expf(-100.0f * dsn) + 1e-10f;
        }
        w16[iq] = wv_;
      }
#pragma unroll
      for (int qd = 0; qd < 4; ++qd)
        *(float4*)&wl[j][qd * 4] = *(float4*)&w16[qd * 4];
    }
    __syncthreads();
    // wave wv owns i = c*16 + 4*wv + e; lane covers h cols 4*h4.., j-range jsub
    f32x4 a0 = {0.f, 0.f, 0.f, 0.f}, a1 = a0, a2 = a0, a3 = a0;
    f32x4 ws = {0.f, 0.f, 0.f, 0.f};
    int jje = jmaxc - 64 * jsub;
    if (jje > 64) jje = 64;
#pragma unroll 4
    for (int jj = 0; jj < jje; ++jj) {
      int jr = 64 * jsub + jj;
      float4 o4 = *(const float4*)&outU[jr][h4 * 4];
      float4 w4 = *(const float4*)&wl[jr][wv * 4];
      a0.x += w4.x * o4.x; a0.y += w4.x * o4.y; a0.z += w4.x * o4.z; a0.w += w4.x * o4.w;
      a1.x += w4.y * o4.x; a1.y += w4.y * o4.y; a1.z += w4.y * o4.z; a1.w += w4.y * o4.w;
      a2.x += w4.z * o4.x; a2.y += w4.z * o4.y; a2.z += w4.z * o4.z; a2.w += w4.z * o4.w;
      a3.x += w4.w * o4.x; a3.y += w4.w * o4.y; a3.z += w4.w * o4.z; a3.w += w4.w * o4.w;
      ws.x += w4.x; ws.y += w4.y; ws.z += w4.z; ws.w += w4.w;
    }
#pragma unroll
    for (int m = 16; m <= 32; m <<= 1) {
      a0.x += __shfl_xor(a0.x, m); a0.y += __shfl_xor(a0.y, m);
      a0.z += __shfl_xor(a0.z, m); a0.w += __shfl_xor(a0.w, m);
      a1.x += __shfl_xor(a1.x, m); a1.y += __shfl_xor(a1.y, m);
      a1.z += __shfl_xor(a1.z, m); a1.w += __shfl_xor(a1.w, m);
      a2.x += __shfl_xor(a2.x, m); a2.y += __shfl_xor(a2.y, m);
      a2.z += __shfl_xor(a2.z, m); a2.w += __shfl_xor(a2.w, m);
      a3.x += __shfl_xor(a3.x, m); a3.y += __shfl_xor(a3.y, m);
      a3.z += __shfl_xor(a3.z, m); a3.w += __shfl_xor(a3.w, m);
      ws.x += __shfl_xor(ws.x, m); ws.y += __shfl_xor(ws.y, m);
      ws.z += __shfl_xor(ws.z, m); ws.w += __shfl_xor(ws.w, m);
    }
    if (jsub == 0) {
      f32x4 accs[4] = {a0, a1, a2, a3};
#pragma unroll
      for (int e = 0; e < 4; ++e) {
        int i = c * 16 + 4 * wv + e;
        float rs = 1.f / ws[e];
        float4 o;
        o.x = accs[e][0] * rs; o.y = accs[e][1] * rs;
        o.z = accs[e][2] * rs; o.w = accs[e][3] * rs;
        *(float4*)&out_w[((size_t)i * U_N + u) * H_N + h4 * 4] = o;
      }
    }
    __syncthreads();
  }
}

// ---- FC: y = out_w @ fc_W[0:64] + ub  (bf16 MFMA) ---------------------------
__global__ __launch_bounds__(256) void k_fc(
    const float* __restrict__ A, const short* __restrict__ Bp,
    const float* __restrict__ ub, float* __restrict__ C) {
  int bm = blockIdx.y, bn = blockIdx.x;
  int tid = threadIdx.x;
  int wave = tid >> 6, lane = tid & 63;
  int wm = wave >> 1, wn = wave & 1;
  int row0 = bm * 128 + wm * 64;
  int col0 = bn * 128 + wn * 64;
  int lr = lane & 15, lk = lane >> 4;
  f32x4 acc[4][4] = {};
#pragma unroll
  for (int ks = 0; ks < 2; ++ks) {
    short8 af[4];
#pragma unroll
    for (int m = 0; m < 4; ++m) {
      const float* ap = &A[((size_t)(row0 + m * 16 + lr)) * H_N + ks * 32 + lk * 8];
      float4 v0 = *(const float4*)ap;
      float4 v1 = *(const float4*)(ap + 4);
      af[m] = pack8(v0, v1);
    }
#pragma unroll
    for (int n = 0; n < 4; ++n) {
      short8 bf = *(const short8*)&Bp[((size_t)((ks * 4 + lk) * P_N + col0 + n * 16 + lr)) * 8];
#pragma unroll
      for (int m = 0; m < 4; ++m)
        acc[m][n] = MFMA(af[m], bf, acc[m][n], 0, 0, 0);
    }
  }
#pragma unroll
  for (int m = 0; m < 4; ++m) {
    int rbase = row0 + m * 16 + lk * 4;
#pragma unroll
    for (int n = 0; n < 4; ++n) {
      int c = col0 + n * 16 + lr;
#pragma unroll
      for (int r = 0; r < 4; ++r) {
        int row = rbase + r;
        int uu = row & (U_N - 1);
        C[(size_t)row * P_N + c] = acc[m][n][r] + ub[uu * P_N + c];
      }
    }
  }
}

extern "C" void kernel_launch(void* const* d_in, const int* in_sizes, int n_in,
                              void* d_out, int out_size, void* d_ws, size_t ws_size,
                              hipStream_t stream) {
  const int*   x           = (const int*)d_in[0];
  const float* t           = (const float*)d_in[1];
  const float* s           = (const float*)d_in[3];
  const float* h0          = (const float*)d_in[5];
  const int*   active_user = (const int*)d_in[6];
  const float* poi_emb     = (const float*)d_in[7];
  const float* user_emb    = (const float*)d_in[8];
  const float* Wx          = (const float*)d_in[9];
  const float* Wh          = (const float*)d_in[10];
  const float* b           = (const float*)d_in[11];
  const float* fcW         = (const float*)d_in[12];
  const float* fcb         = (const float*)d_in[13];

  float* y_out = (float*)d_out;
  float* hT = y_out + (size_t)T_N * U_N * P_N;

  char* ws = (char*)d_ws;
  float* out_buf = (float*)ws;                          // 33,554,432 B
  float* outw    = (float*)(ws + 33554432);             // 33,554,432 B
  float* ub      = (float*)(ws + 67108864);             // 2,097,152 B
  short* bp      = (short*)(ws + 69206016);             // 131,072 B
  short* wxp     = (short*)(ws + 69337088);             // 24,576 B
  short* whp     = (short*)(ws + 69361664);             // 24,576 B

  k_wpack<<<12, 256, 0, stream>>>(Wx, Wh, wxp, whp);
  k_scan<<<32, 256, 0, stream>>>(x, poi_emb, h0, wxp, whp, b, out_buf, hT);
  k_ub<<<U_N, 256, 0, stream>>>(active_user, user_emb, fcW, fcb, ub);
  k_bpack<<<32, 256, 0, stream>>>(fcW, bp);
  k_stage2<<<U_N, 256, 0, stream>>>(t, s, out_buf, outw);
  k_fc<<<dim3(8, 1024), 256, 0, stream>>>(outw, bp, ub, y_out);
}

// Round 3
// 575.171 us; speedup vs baseline: 1.2537x; 1.2195x over previous
//
#include <hip/hip_runtime.h>

#define T_N 256
#define U_N 512
#define H_N 64
#define P_N 1024

typedef __attribute__((ext_vector_type(8))) short short8;
typedef __attribute__((ext_vector_type(4))) short short4v;
typedef __attribute__((ext_vector_type(4))) float f32x4;

#define MFMA __builtin_amdgcn_mfma_f32_16x16x32_bf16

__device__ __forceinline__ short f2bf(float f) {
  union { float f; unsigned u; } v; v.f = f;
  unsigned r = v.u + 0x7FFFu + ((v.u >> 16) & 1u);
  return (short)(r >> 16);
}

__device__ __forceinline__ short8 pack8(float4 a, float4 b) {
  short8 r;
  r[0] = f2bf(a.x); r[1] = f2bf(a.y); r[2] = f2bf(a.z); r[3] = f2bf(a.w);
  r[4] = f2bf(b.x); r[5] = f2bf(b.y); r[6] = f2bf(b.z); r[7] = f2bf(b.w);
  return r;
}

// ---- pack Wx/Wh into scan B-frags AND fc_W[0:64] into permuted fc B-frags ---
// blocks 0..11: wp[((ks*4+lk)*192+g)*8+e] = W[ks*32+lk*8+e][g]
// blocks 12..43: bp[slot s]: logical col L = (s&~63) + 4*(s&15) + ((s>>4)&3)
__global__ __launch_bounds__(256) void k_pack(
    const float* __restrict__ Wx, const float* __restrict__ Wh,
    const float* __restrict__ fcW, short* __restrict__ wxp,
    short* __restrict__ whp, short* __restrict__ bp) {
  if (blockIdx.x < 12) {
    int idx = blockIdx.x * 256 + threadIdx.x;  // 3072 = 2*1536
    int m = idx / 1536;
    int r = idx % 1536;
    const float* W = m ? Wh : Wx;
    short* op = m ? whp : wxp;
    int ks = r / 768, lk = (r / 192) & 3, g = r % 192;
#pragma unroll
    for (int e = 0; e < 8; ++e)
      op[(size_t)r * 8 + e] = f2bf(W[(ks * 32 + lk * 8 + e) * 192 + g]);
  } else {
    int sidx = (blockIdx.x - 12) * 256 + threadIdx.x;  // 0..8191
    int s = sidx & 1023;
    int kg = (sidx >> 10) & 3;
    int ks = sidx >> 12;
    int L = (s & ~63) + 4 * (s & 15) + ((s >> 4) & 3);
#pragma unroll
    for (int e = 0; e < 8; ++e) {
      int k = ks * 32 + kg * 8 + e;
      bp[((size_t)((ks * 4 + kg) * P_N + s)) * 8 + e] = f2bf(fcW[k * P_N + L]);
    }
  }
}

// ---- fused GRU scan: 32 blocks x 16 users, MFMA gates -----------------------
__global__ __launch_bounds__(256) void k_scan(
    const int* __restrict__ x, const float* __restrict__ poi_emb,
    const float* __restrict__ h0, const short* __restrict__ wxp,
    const short* __restrict__ whp, const float* __restrict__ b,
    float* __restrict__ out, float* __restrict__ hT) {
  int u0 = blockIdx.x * 16;
  int tid = threadIdx.x;
  int w = tid >> 6, lane = tid & 63, lr = lane & 15, lk = lane >> 4;
  __shared__ __align__(16) float h_lds[2][16][68];
  int sgr = 16 * w, sgz = 64 + 16 * w, sgn = 128 + 16 * w;
  short8 fxr[2], fxz[2], fxn[2], fhr[2], fhz[2], fhn[2];
#pragma unroll
  for (int ks = 0; ks < 2; ++ks) {
    size_t base = (size_t)((ks * 4 + lk) * 192) * 8;
    fxr[ks] = *(const short8*)&wxp[base + (size_t)(sgr + lr) * 8];
    fxz[ks] = *(const short8*)&wxp[base + (size_t)(sgz + lr) * 8];
    fxn[ks] = *(const short8*)&wxp[base + (size_t)(sgn + lr) * 8];
    fhr[ks] = *(const short8*)&whp[base + (size_t)(sgr + lr) * 8];
    fhz[ks] = *(const short8*)&whp[base + (size_t)(sgz + lr) * 8];
    fhn[ks] = *(const short8*)&whp[base + (size_t)(sgn + lr) * 8];
  }
  float br = b[sgr + lr], bz = b[sgz + lr], bn = b[sgn + lr];
  for (int idx = tid; idx < 16 * 64; idx += 256)
    h_lds[0][idx >> 6][idx & 63] = h0[(size_t)(u0 + (idx >> 6)) * H_N + (idx & 63)];
  __syncthreads();
  float hp[4];
#pragma unroll
  for (int e = 0; e < 4; ++e) hp[e] = h_lds[0][4 * lk + e][16 * w + lr];
  short8 ah0, ah1;
  {
    float4 q0 = *(float4*)&h_lds[0][lr][8 * lk];
    float4 q1 = *(float4*)&h_lds[0][lr][8 * lk + 4];
    float4 q2 = *(float4*)&h_lds[0][lr][32 + 8 * lk];
    float4 q3 = *(float4*)&h_lds[0][lr][32 + 8 * lk + 4];
    ah0 = pack8(q0, q1); ah1 = pack8(q2, q3);
  }
  int xic = x[u0 + lr];
  float4 p0, p1, p2, p3;
  {
    const float* pb = poi_emb + (size_t)xic * H_N + lk * 8;
    p0 = *(const float4*)pb; p1 = *(const float4*)(pb + 4);
    p2 = *(const float4*)(pb + 32); p3 = *(const float4*)(pb + 36);
  }
  int xin = x[U_N + u0 + lr];
  for (int t = 0; t < T_N; ++t) {
    short8 ax0 = pack8(p0, p1), ax1 = pack8(p2, p3);
    if (t + 1 < T_N) {
      const float* pb = poi_emb + (size_t)xin * H_N + lk * 8;
      p0 = *(const float4*)pb; p1 = *(const float4*)(pb + 4);
      p2 = *(const float4*)(pb + 32); p3 = *(const float4*)(pb + 36);
      int tn = (t + 2 < T_N) ? t + 2 : T_N - 1;
      xin = x[(size_t)tn * U_N + u0 + lr];
    }
    f32x4 accr = {br, br, br, br};
    f32x4 accz = {bz, bz, bz, bz};
    f32x4 accnx = {bn, bn, bn, bn};
    f32x4 accnh = {0.f, 0.f, 0.f, 0.f};
    accr = MFMA(ax0, fxr[0], accr, 0, 0, 0);
    accr = MFMA(ax1, fxr[1], accr, 0, 0, 0);
    accz = MFMA(ax0, fxz[0], accz, 0, 0, 0);
    accz = MFMA(ax1, fxz[1], accz, 0, 0, 0);
    accnx = MFMA(ax0, fxn[0], accnx, 0, 0, 0);
    accnx = MFMA(ax1, fxn[1], accnx, 0, 0, 0);
    accr = MFMA(ah0, fhr[0], accr, 0, 0, 0);
    accr = MFMA(ah1, fhr[1], accr, 0, 0, 0);
    accz = MFMA(ah0, fhz[0], accz, 0, 0, 0);
    accz = MFMA(ah1, fhz[1], accz, 0, 0, 0);
    accnh = MFMA(ah0, fhn[0], accnh, 0, 0, 0);
    accnh = MFMA(ah1, fhn[1], accnh, 0, 0, 0);
    int wbuf = (t & 1) ^ 1;
#pragma unroll
    for (int e = 0; e < 4; ++e) {
      float r = 1.f / (1.f + __expf(-accr[e]));
      float z = 1.f / (1.f + __expf(-accz[e]));
      float npre = accnx[e] + r * accnh[e];
      float e2 = __expf(2.f * npre);
      float n = 1.f - 2.f / (e2 + 1.f);
      float hn = hp[e] + z * (n - hp[e]);
      hp[e] = hn;
      h_lds[wbuf][4 * lk + e][16 * w + lr] = hn;
      out[((size_t)t * U_N + u0 + 4 * lk + e) * H_N + 16 * w + lr] = hn;
    }
    __syncthreads();
    {
      float4 q0 = *(float4*)&h_lds[wbuf][lr][8 * lk];
      float4 q1 = *(float4*)&h_lds[wbuf][lr][8 * lk + 4];
      float4 q2 = *(float4*)&h_lds[wbuf][lr][32 + 8 * lk];
      float4 q3 = *(float4*)&h_lds[wbuf][lr][32 + 8 * lk + 4];
      ah0 = pack8(q0, q1); ah1 = pack8(q2, q3);
    }
  }
  for (int idx = tid; idx < 16 * 64; idx += 256)
    hT[(size_t)(u0 + (idx >> 6)) * H_N + (idx & 63)] = h_lds[0][idx >> 6][idx & 63];
}

// ---- per-user bias: ub[u,p] = fc_b[p] + p_u . fc_W[64:128] ------------------
__global__ __launch_bounds__(256) void k_ub(
    const int* __restrict__ active_user, const float* __restrict__ user_emb,
    const float* __restrict__ fcW, const float* __restrict__ fcb,
    float* __restrict__ ub) {
  int u = blockIdx.x;
  int tid = threadIdx.x;
  __shared__ float pu[H_N];
  if (tid < H_N) pu[tid] = user_emb[active_user[u] * H_N + tid];
  __syncthreads();
  for (int p = tid; p < P_N; p += 256) {
    float acc = fcb[p];
#pragma unroll
    for (int k = 0; k < H_N; ++k) acc += pu[k] * fcW[(H_N + k) * P_N + p];
    ub[u * P_N + p] = acc;
  }
}

// ---- decay-weighted sum; emits bf16 A rows (row-major, ready for fc MFMA) ---
__global__ __launch_bounds__(256) void k_stage2(
    const float* __restrict__ t, const float* __restrict__ s,
    const float* __restrict__ out, short* __restrict__ apk) {
  int u = blockIdx.x;
  int tid = threadIdx.x;
  __shared__ __align__(16) float outU[T_N][68];
  __shared__ __align__(16) float wl[T_N][20];
  __shared__ float tU[T_N];
  __shared__ float sUx[T_N], sUy[T_N];
  for (int idx = tid; idx < T_N * 16; idx += 256) {
    int jr = idx >> 4, q = idx & 15;
    *(float4*)&outU[jr][q * 4] =
        *(const float4*)&out[((size_t)jr * U_N + u) * H_N + q * 4];
  }
  {
    int jr = tid;
    tU[jr] = t[jr * U_N + u];
    sUx[jr] = s[((size_t)jr * U_N + u) * 2];
    sUy[jr] = s[((size_t)jr * U_N + u) * 2 + 1];
  }
  __syncthreads();
  int lane = tid & 63, wv = tid >> 6;
  int h4 = lane & 15, jsub = lane >> 4;
  int j = tid;
  float tj = tU[j], sx = sUx[j], sy = sUy[j];
  for (int c = 0; c < 16; ++c) {
    int jmaxc = c * 16 + 16;
    if (j < jmaxc) {
      float w16[16];
#pragma unroll
      for (int iq = 0; iq < 16; ++iq) {
        int i = c * 16 + iq;
        float wv_ = 0.f;
        if (j <= i) {
          float dt = tU[i] - tj;
          float dx = sUx[i] - sx, dy = sUy[i] - sy;
          float dsn = sqrtf(dx * dx + dy * dy);
          float ft = 0.5f * (__cosf(dt * 7.2722052166430395e-05f) + 1.0f) *
                     __expf(dt * (-1.1574074074074074e-06f));
          wv_ = ft * __expf(-100.0f * dsn) + 1e-10f;
        }
        w16[iq] = wv_;
      }
#pragma unroll
      for (int qd = 0; qd < 4; ++qd)
        *(float4*)&wl[j][qd * 4] = *(float4*)&w16[qd * 4];
    }
    __syncthreads();
    f32x4 a0 = {0.f, 0.f, 0.f, 0.f}, a1 = a0, a2 = a0, a3 = a0;
    f32x4 ws = {0.f, 0.f, 0.f, 0.f};
    int jje = jmaxc - 64 * jsub;
    if (jje > 64) jje = 64;
#pragma unroll 4
    for (int jj = 0; jj < jje; ++jj) {
      int jr = 64 * jsub + jj;
      float4 o4 = *(const float4*)&outU[jr][h4 * 4];
      float4 w4 = *(const float4*)&wl[jr][wv * 4];
      a0.x += w4.x * o4.x; a0.y += w4.x * o4.y; a0.z += w4.x * o4.z; a0.w += w4.x * o4.w;
      a1.x += w4.y * o4.x; a1.y += w4.y * o4.y; a1.z += w4.y * o4.z; a1.w += w4.y * o4.w;
      a2.x += w4.z * o4.x; a2.y += w4.z * o4.y; a2.z += w4.z * o4.z; a2.w += w4.z * o4.w;
      a3.x += w4.w * o4.x; a3.y += w4.w * o4.y; a3.z += w4.w * o4.z; a3.w += w4.w * o4.w;
      ws.x += w4.x; ws.y += w4.y; ws.z += w4.z; ws.w += w4.w;
    }
#pragma unroll
    for (int m = 16; m <= 32; m <<= 1) {
      a0.x += __shfl_xor(a0.x, m); a0.y += __shfl_xor(a0.y, m);
      a0.z += __shfl_xor(a0.z, m); a0.w += __shfl_xor(a0.w, m);
      a1.x += __shfl_xor(a1.x, m); a1.y += __shfl_xor(a1.y, m);
      a1.z += __shfl_xor(a1.z, m); a1.w += __shfl_xor(a1.w, m);
      a2.x += __shfl_xor(a2.x, m); a2.y += __shfl_xor(a2.y, m);
      a2.z += __shfl_xor(a2.z, m); a2.w += __shfl_xor(a2.w, m);
      a3.x += __shfl_xor(a3.x, m); a3.y += __shfl_xor(a3.y, m);
      a3.z += __shfl_xor(a3.z, m); a3.w += __shfl_xor(a3.w, m);
      ws.x += __shfl_xor(ws.x, m); ws.y += __shfl_xor(ws.y, m);
      ws.z += __shfl_xor(ws.z, m); ws.w += __shfl_xor(ws.w, m);
    }
    if (jsub == 0) {
      f32x4 accs[4] = {a0, a1, a2, a3};
#pragma unroll
      for (int e = 0; e < 4; ++e) {
        int i = c * 16 + 4 * wv + e;
        float rs = 1.f / ws[e];
        short4v ov;
        ov[0] = f2bf(accs[e][0] * rs); ov[1] = f2bf(accs[e][1] * rs);
        ov[2] = f2bf(accs[e][2] * rs); ov[3] = f2bf(accs[e][3] * rs);
        *(short4v*)&apk[((size_t)i * U_N + u) * H_N + h4 * 4] = ov;
      }
    }
    __syncthreads();
  }
}

// ---- FC: y = A(bf16) @ fc_W[0:64] + ub; float4 nontemporal C stores ---------
__global__ __launch_bounds__(256) void k_fc(
    const short* __restrict__ apk, const short* __restrict__ Bp,
    const float* __restrict__ ub, float* __restrict__ C) {
  int bm = blockIdx.y, bn = blockIdx.x;
  int tid = threadIdx.x;
  int wave = tid >> 6, lane = tid & 63;
  int wm = wave >> 1, wn = wave & 1;
  int row0 = bm * 128 + wm * 64;
  int col0 = bn * 128 + wn * 64;
  int lr = lane & 15, lk = lane >> 4;
  f32x4 acc[4][4] = {};
#pragma unroll
  for (int ks = 0; ks < 2; ++ks) {
    short8 af[4];
#pragma unroll
    for (int m = 0; m < 4; ++m)
      af[m] = *(const short8*)&apk[((size_t)(row0 + m * 16 + lr)) * H_N + ks * 32 + lk * 8];
#pragma unroll
    for (int n = 0; n < 4; ++n) {
      short8 bf = *(const short8*)&Bp[((size_t)((ks * 4 + lk) * P_N + col0 + n * 16 + lr)) * 8];
#pragma unroll
      for (int m = 0; m < 4; ++m)
        acc[m][n] = MFMA(af[m], bf, acc[m][n], 0, 0, 0);
    }
  }
#pragma unroll
  for (int m = 0; m < 4; ++m) {
    int rbase = row0 + m * 16 + lk * 4;
#pragma unroll
    for (int r = 0; r < 4; ++r) {
      int row = rbase + r;
      int uu = row & (U_N - 1);
      f32x4 ubv = *(const f32x4*)&ub[(size_t)uu * P_N + col0 + 4 * lr];
      f32x4 v;
      v[0] = acc[m][0][r] + ubv[0];
      v[1] = acc[m][1][r] + ubv[1];
      v[2] = acc[m][2][r] + ubv[2];
      v[3] = acc[m][3][r] + ubv[3];
      __builtin_nontemporal_store(v, (f32x4*)&C[(size_t)row * P_N + col0 + 4 * lr]);
    }
  }
}

extern "C" void kernel_launch(void* const* d_in, const int* in_sizes, int n_in,
                              void* d_out, int out_size, void* d_ws, size_t ws_size,
                              hipStream_t stream) {
  const int*   x           = (const int*)d_in[0];
  const float* t           = (const float*)d_in[1];
  const float* s           = (const float*)d_in[3];
  const float* h0          = (const float*)d_in[5];
  const int*   active_user = (const int*)d_in[6];
  const float* poi_emb     = (const float*)d_in[7];
  const float* user_emb    = (const float*)d_in[8];
  const float* Wx          = (const float*)d_in[9];
  const float* Wh          = (const float*)d_in[10];
  const float* b           = (const float*)d_in[11];
  const float* fcW         = (const float*)d_in[12];
  const float* fcb         = (const float*)d_in[13];

  float* y_out = (float*)d_out;
  float* hT = y_out + (size_t)T_N * U_N * P_N;

  char* ws = (char*)d_ws;
  float* out_buf = (float*)ws;                          // 33,554,432 B
  short* apk     = (short*)(ws + 33554432);             // 16,777,216 B
  float* ub      = (float*)(ws + 50331648);             // 2,097,152 B
  short* bp      = (short*)(ws + 52428800);             // 131,072 B
  short* wxp     = (short*)(ws + 52559872);             // 24,576 B
  short* whp     = (short*)(ws + 52584448);             // 24,576 B

  k_pack<<<44, 256, 0, stream>>>(Wx, Wh, fcW, wxp, whp, bp);
  k_scan<<<32, 256, 0, stream>>>(x, poi_emb, h0, wxp, whp, b, out_buf, hT);
  k_ub<<<U_N, 256, 0, stream>>>(active_user, user_emb, fcW, fcb, ub);
  k_stage2<<<U_N, 256, 0, stream>>>(t, s, out_buf, apk);
  k_fc<<<dim3(8, 1024), 256, 0, stream>>>(apk, bp, ub, y_out);
}